// Round 12
// baseline (1414.499 us; speedup 1.0000x reference)
//
#include <hip/hip_runtime.h>
#include <hip/hip_bf16.h>

#define NPTS 600000
#define NKEYS (1 << 22)          // 2 * 128^3 compact key space
#define CHUNK 4096
#define NPART (NKEYS / CHUNK)    // 1024

typedef unsigned int u32;
typedef unsigned long long u64;
typedef unsigned short u16;
typedef __attribute__((ext_vector_type(8))) short short8;   // 8 bf16 = 4 VGPRs
typedef __attribute__((ext_vector_type(4))) float f32x4;

__device__ __forceinline__ u16 f2bf(float x) {
  union { float f; u32 u; } c; c.f = x;
  u32 r = c.u + 0x7fffu + ((c.u >> 16) & 1u);   // RNE, inputs finite
  return (u16)(r >> 16);
}

// ---- K0a: fold BN into alpha/beta -------------------------------------------
__global__ void k0a_bn(const float* __restrict__ s, const float* __restrict__ b,
                       const float* __restrict__ m, const float* __restrict__ v,
                       float* __restrict__ ab) {
  int c = threadIdx.x;   // 64 threads
  float a = s[c] * rsqrtf(v[c] + 1e-5f);
  ab[c] = a;
  ab[64 + c] = b[c] - m[c] * a;
}

// ---- K0b: W[27][cin][cout] f32 -> Wt[27][cout][cin] bf16 --------------------
__global__ void k0b_wt(const float* __restrict__ W, u16* __restrict__ Wt) {
  int e = blockIdx.x * 256 + threadIdx.x;
  if (e >= 27 * 4096) return;
  int k = e >> 12, rem = e & 4095, cin = rem >> 6, cout = rem & 63;
  Wt[(k << 12) + (cout << 6) + cin] = f2bf(W[e]);
}

// ---- K1: compact keys + per-voxel point counts ------------------------------
__global__ void k1_keys(const int* __restrict__ coords, int* __restrict__ keys,
                        u32* __restrict__ lut) {
  int i = blockIdx.x * 256 + threadIdx.x;
  if (i >= NPTS) return;
  int4 c4 = *(const int4*)(coords + i * 4);
  int k = (c4.w << 21) | ((c4.x >> 1) << 14) | ((c4.y >> 1) << 7) | (c4.z >> 1);
  keys[i] = k;
  atomicAdd(&lut[k], 1u);   // count points per voxel (~600k atomics total)
}

// ---- K2a: per-chunk occupied-voxel counts -----------------------------------
__global__ void k2a_part(const u32* __restrict__ lut, u32* __restrict__ partials) {
  __shared__ u32 sd[256];
  int blk = blockIdx.x, t = threadIdx.x;
  const u32* p = lut + blk * CHUNK;
  u32 s = 0;
  for (int j = t; j < CHUNK; j += 256) s += (p[j] != 0u);
  sd[t] = s; __syncthreads();
  for (int o = 128; o > 0; o >>= 1) { if (t < o) sd[t] += sd[t + o]; __syncthreads(); }
  if (t == 0) partials[blk] = sd[0];
}

// ---- K2b: scan the 1024 partials (exclusive) + total U ----------------------
__global__ void k2b_top(u32* __restrict__ partials) {
  __shared__ u32 sh[NPART];
  int t = threadIdx.x;   // 1024 threads
  u32 x = partials[t];
  sh[t] = x; __syncthreads();
  for (int off = 1; off < NPART; off <<= 1) {
    u32 add = (t >= off) ? sh[t - off] : 0u;
    __syncthreads();
    sh[t] += add;
    __syncthreads();
  }
  partials[t] = sh[t] - x;                       // exclusive
  if (t == NPART - 1) partials[NPART] = sh[t];   // total unique count U
}

// ---- K2c: fill lut ((rank+1)|multi<<31 or 0), r2k, zero multi f32 rows ------
__global__ void k2c_fill(u32* __restrict__ lut, const u32* __restrict__ partials,
                         int* __restrict__ r2k, float* __restrict__ fds32) {
  __shared__ u32 tsum[256];
  int blk = blockIdx.x, t = threadIdx.x;
  int base = blk * CHUNK + t * 16;
  u32 loc[16]; u32 s = 0;
#pragma unroll
  for (int j = 0; j < 16; j++) { loc[j] = lut[base + j]; s += (loc[j] != 0u); }
  tsum[t] = s; __syncthreads();
  for (int off = 1; off < 256; off <<= 1) {
    u32 add = (t >= off) ? tsum[t - off] : 0u;
    __syncthreads();
    tsum[t] += add;
    __syncthreads();
  }
  u32 rank = partials[blk] + tsum[t] - s;   // exclusive rank for first elem
#pragma unroll
  for (int j = 0; j < 16; j++) {
    if (loc[j]) {
      u32 flag = (loc[j] > 1u) ? 0x80000000u : 0u;
      lut[base + j] = (rank + 1u) | flag;
      r2k[rank] = base + j;
      if (flag) {   // zero the f32 accumulation row for multi-point voxels
        float4 z = {0.f, 0.f, 0.f, 0.f};
        float* d = fds32 + ((size_t)rank << 6);
#pragma unroll
        for (int c = 0; c < 16; c++) *(float4*)(d + c * 4) = z;
      }
      rank++;
    } else lut[base + j] = 0u;
  }
}

// ---- K3: fused segment-sum: singles -> bf16 direct, multis -> f32 atomics ---
__global__ void k3_seg(const float* __restrict__ feats, const int* __restrict__ keys,
                       const u32* __restrict__ lut, float* __restrict__ fds32,
                       u16* __restrict__ fdsb) {
  int idx = blockIdx.x * 256 + threadIdx.x;   // NPTS*16 threads, 4 ch each
  if (idx >= NPTS * 16) return;
  int i = idx >> 4, q = (idx & 15) << 2;
  u32 lv = lut[keys[i]];
  u32 r = (lv & 0x7fffffffu) - 1u;
  float4 v = *(const float4*)(feats + (size_t)i * 64 + q);
  if (lv >> 31) {               // ~13% of points: shared voxel, accumulate f32
    float* dst = fds32 + ((size_t)r << 6) + q;
    atomicAdd(dst + 0, v.x); atomicAdd(dst + 1, v.y);
    atomicAdd(dst + 2, v.z); atomicAdd(dst + 3, v.w);
  } else {                      // ~87%: sole occupant, convert + plain store
    ushort4 o;
    o.x = f2bf(v.x); o.y = f2bf(v.y); o.z = f2bf(v.z); o.w = f2bf(v.w);
    *(ushort4*)(fdsb + ((size_t)r << 6) + q) = o;
  }
}

// ---- K3b: convert only multi-voxel rows f32 -> bf16 -------------------------
__global__ void k3b_fix(const int* __restrict__ r2k, const u32* __restrict__ lut,
                        const u32* __restrict__ pU,
                        const float* __restrict__ fds32, u16* __restrict__ fdsb) {
  int idx = blockIdx.x * 256 + threadIdx.x;   // NPTS*4 threads, 16 ch each
  int r = idx >> 2;
  if (r >= (int)(*pU)) return;
  u32 lv = lut[r2k[r]];
  if (!(lv >> 31)) return;
  int q = (idx & 3) << 4;
  const float* src = fds32 + ((size_t)r << 6) + q;
  u16* dst = fdsb + ((size_t)r << 6) + q;
#pragma unroll
  for (int j = 0; j < 4; j++) {
    float4 v = *(const float4*)(src + j * 4);
    ushort4 o;
    o.x = f2bf(v.x); o.y = f2bf(v.y); o.z = f2bf(v.z); o.w = f2bf(v.w);
    *(ushort4*)(dst + j * 4) = o;
  }
}

// ---- K4: rulebook-compacted gather-GEMM + BN/ReLU (barrier-free core) -------
// Block = 512 thr (8 waves), 128 output rows. Phase A: 3456 probes by free-
// running threads; hits compacted into per-k LDS lists (ballot + one
// atomicAdd per wave). Phase B (NO barriers): wave w owns k = w, w+8, ...;
// per k: B = Wt[k] in regs, hit-list processed in groups of 16 -> A-frags
// gathered ONLY for hits (pads read zero row), 8 MFMA/group, D scatter-added
// into LDS f32 acc (stride 68 = bank-spread + 16B aligned; ds atomics cover
// cross-k races; fp32 add-order wobble ~1e-6 << threshold). Phase C: BN+ReLU.
// Entry packing: (local_row << 20) | in_rank  (in_rank < 2^20, lr < 128;
// pad = (128<<20)|NPTS -> zero A row, dummy acc row 128).
#define K4_ROWS 128
#define ACCW 68
__global__ __launch_bounds__(512) void k4_conv(
    const u32* __restrict__ lut, const int* __restrict__ r2k,
    const u16* __restrict__ fdsb, const u16* __restrict__ Wt,
    const u32* __restrict__ pU, const float* __restrict__ ab,
    float* __restrict__ out) {
  __shared__ int  keyL[K4_ROWS];
  __shared__ u32  cntL[32];
  __shared__ u32  listL[27 * K4_ROWS];
  __shared__ __align__(16) float accL[129][ACCW];
  const u32 U = *pU;
  int tid = threadIdx.x;
  // XCD-bijective swizzle (grid multiple of 8): rank-contiguous chunks per XCD.
  int bid = blockIdx.x;
  int cpx = (int)gridDim.x >> 3;
  int swz = (bid & 7) * cpx + (bid >> 3);
  int rbase = swz * K4_ROWS;

  // ---- phase A0: init ----
  if (tid < K4_ROWS) {
    int r = rbase + tid;
    keyL[tid] = ((u32)r < U) ? r2k[r] : -1;
  }
  if (tid < 32) cntL[tid] = 0;
  for (int i = tid; i < 129 * ACCW; i += 512) ((float*)accL)[i] = 0.f;
  __syncthreads();

  // ---- phase A1: probes + wave-compacted list build ----
  int lane = tid & 63;
  u64 ltmask = (lane == 63) ? ~0ull >> 1 : ((1ull << ((lane & 63) + 1)) - 1) >> 1;
  for (int p = tid; p < 27 * K4_ROWS; p += 512) {
    int k = p >> 7, lr = p & 127;          // k uniform across the wave
    int key = keyL[lr];
    int dx = k / 9 - 1, dy = (k / 3) % 3 - 1, dz = k % 3 - 1;
    int zz = key & 127, yy = (key >> 7) & 127, xx = (key >> 14) & 127;
    int nx = xx + dx, ny = yy + dy, nz = zz + dz;
    bool ok = (key >= 0) & ((u32)nx < 128u) & ((u32)ny < 128u) & ((u32)nz < 128u);
    int a = ok ? (key + dx * 16384 + dy * 128 + dz) : NKEYS;  // sentinel -> 0
    u32 lv = lut[a];
    u64 hits = __ballot(lv != 0u);
    if (lv) {
      u32 pre = (u32)__popcll(hits & ltmask);
      u32 base;
      if (pre == 0) base = atomicAdd(&cntL[k], (u32)__popcll(hits));
      base = __shfl(base, (int)(__ffsll((long long)hits) - 1));
      listL[(k << 7) + base + pre] = ((u32)lr << 20) | ((lv & 0x7fffffffu) - 1u);
    }
  }
  __syncthreads();

  // ---- phase B: grouped MFMA, barrier-free; wave w owns k = w, w+8, ... ----
  int w = tid >> 6, l = lane;
  int col = l & 15, kg = l >> 4;
  for (int k = w; k < 27; k += 8) {
    int cnt = (int)cntL[k];
    if (cnt == 0) continue;
    const u16* wk = Wt + (k << 12);
    short8 bf[4][2];
#pragma unroll
    for (int ct = 0; ct < 4; ct++)
#pragma unroll
      for (int h = 0; h < 2; h++)
        bf[ct][h] = *(const short8*)(wk + (((ct << 4) + col) << 6) + (h << 5) + (kg << 3));
    for (int g = 0; g * 16 < cnt; g++) {
      int s = (g << 4) + col;   // lane's A slot
      u32 e = (s < cnt) ? listL[(k << 7) + s] : (((u32)128 << 20) | (u32)NPTS);
      const u16* fr = fdsb + ((size_t)(e & 0xFFFFFu) << 6) + (kg << 3);
      short8 a0 = *(const short8*)(fr);
      short8 a1 = *(const short8*)(fr + 32);
      u32 lr_i[4];              // acc rows for D slots kg*4+i
#pragma unroll
      for (int i = 0; i < 4; i++) {
        int si = (g << 4) + (kg << 2) + i;
        u32 ei = (si < cnt) ? listL[(k << 7) + si] : ((u32)128 << 20);
        lr_i[i] = ei >> 20;
      }
#pragma unroll
      for (int ct = 0; ct < 4; ct++) {
        f32x4 d = {0.f, 0.f, 0.f, 0.f};
        d = __builtin_amdgcn_mfma_f32_16x16x32_bf16(a0, bf[ct][0], d, 0, 0, 0);
        d = __builtin_amdgcn_mfma_f32_16x16x32_bf16(a1, bf[ct][1], d, 0, 0, 0);
        int c = (ct << 4) + col;
#pragma unroll
        for (int i = 0; i < 4; i++)
          atomicAdd(&accL[lr_i[i]][c], d[i]);
      }
    }
  }
  __syncthreads();

  // ---- phase C: BN + ReLU + store (zeros for invalid rows) ----
  {
    int lr = tid >> 2, q = (tid & 3) << 4;
    int r = rbase + lr;
    if (r < NPTS) {
      bool valid = ((u32)r < U);
      float* op = out + ((size_t)r << 6) + q;
#pragma unroll
      for (int j = 0; j < 4; j++) {
        float4 v = *(const float4*)(&accL[lr][q + j * 4]);
        float4 o;
        float* vv = (float*)&v; float* oo = (float*)&o;
#pragma unroll
        for (int t2 = 0; t2 < 4; t2++) {
          int c = q + j * 4 + t2;
          float y = 0.f;
          if (valid) {
            y = fmaf(vv[t2], ab[c], ab[64 + c]);
            y = y > 0.f ? y : 0.f;
          }
          oo[t2] = y;
        }
        *(float4*)(op + j * 4) = o;
      }
    }
  }
}

extern "C" void kernel_launch(void* const* d_in, const int* in_sizes, int n_in,
                              void* d_out, int out_size, void* d_ws, size_t ws_size,
                              hipStream_t stream) {
  const int*   coords = (const int*)d_in[0];
  const float* feats  = (const float*)d_in[1];
  const float* W      = (const float*)d_in[2];
  const float* bns    = (const float*)d_in[3];
  const float* bnb    = (const float*)d_in[4];
  const float* bnm    = (const float*)d_in[5];
  const float* bnv    = (const float*)d_in[6];
  float* out = (float*)d_out;

  char* ws = (char*)d_ws;
  size_t off = 0;
  auto alloc = [&](size_t bytes) -> void* {
    void* p = ws + off;
    off += (bytes + 255) & ~(size_t)255;
    return p;
  };
  u32* lut      = (u32*)alloc((size_t)(NKEYS + 1) * 4);  // +1 zero sentinel
  u32* partials = (u32*)alloc((NPART + 8) * 4);
  int* keys     = (int*)alloc((size_t)NPTS * 4);
  int* r2k      = (int*)alloc((size_t)NPTS * 4);
  u16* fdsb     = (u16*)alloc((size_t)(NPTS + 1) * 64 * 2);  // +1 zero row
  u16* Wt       = (u16*)alloc((size_t)27 * 4096 * 2);
  float* ab     = (float*)alloc(128 * 4);
  (void)ws_size; (void)out_size; (void)n_in; (void)in_sizes;

  float* fds32 = out;   // d_out doubles as f32 staging for multi-point voxels

  hipMemsetAsync(lut, 0, (size_t)(NKEYS + 1) * 4, stream);
  hipMemsetAsync(fdsb + (size_t)NPTS * 64, 0, 128, stream);   // zero row

  k0a_bn<<<1, 64, 0, stream>>>(bns, bnb, bnm, bnv, ab);
  k0b_wt<<<(27 * 4096 + 255) / 256, 256, 0, stream>>>(W, Wt);
  k1_keys<<<(NPTS + 255) / 256, 256, 0, stream>>>(coords, keys, lut);
  k2a_part<<<NPART, 256, 0, stream>>>(lut, partials);
  k2b_top<<<1, NPART, 0, stream>>>(partials);
  k2c_fill<<<NPART, 256, 0, stream>>>(lut, partials, r2k, fds32);
  k3_seg<<<(NPTS * 16 + 255) / 256, 256, 0, stream>>>(feats, keys, lut, fds32, fdsb);
  k3b_fix<<<(NPTS * 4 + 255) / 256, 256, 0, stream>>>(r2k, lut, partials + NPART, fds32, fdsb);
  // 128 rows per block; 4688 blocks (multiple of 8 for the XCD swizzle)
  k4_conv<<<(NPTS + K4_ROWS - 1) / K4_ROWS, 512, 0, stream>>>(
      lut, r2k, fdsb, Wt, partials + NPART, ab, out);
}

// Round 13
// 637.315 us; speedup vs baseline: 2.2195x; 2.2195x over previous
//
#include <hip/hip_runtime.h>
#include <hip/hip_bf16.h>

#define NPTS 600000
#define NKEYS (1 << 22)          // 2 * 128^3 compact key space
#define CHUNK 4096
#define NPART (NKEYS / CHUNK)    // 1024

typedef unsigned int u32;
typedef unsigned short u16;
typedef __attribute__((ext_vector_type(8))) short short8;   // 8 bf16 = 4 VGPRs
typedef __attribute__((ext_vector_type(4))) float f32x4;

__device__ __forceinline__ u16 f2bf(float x) {
  union { float f; u32 u; } c; c.f = x;
  u32 r = c.u + 0x7fffu + ((c.u >> 16) & 1u);   // RNE, inputs finite
  return (u16)(r >> 16);
}

// ---- K0a: fold BN into alpha/beta -------------------------------------------
__global__ void k0a_bn(const float* __restrict__ s, const float* __restrict__ b,
                       const float* __restrict__ m, const float* __restrict__ v,
                       float* __restrict__ ab) {
  int c = threadIdx.x;   // 64 threads
  float a = s[c] * rsqrtf(v[c] + 1e-5f);
  ab[c] = a;
  ab[64 + c] = b[c] - m[c] * a;
}

// ---- K0b: W[27][cin][cout] f32 -> Wt[27][cout][cin] bf16 --------------------
__global__ void k0b_wt(const float* __restrict__ W, u16* __restrict__ Wt) {
  int e = blockIdx.x * 256 + threadIdx.x;
  if (e >= 27 * 4096) return;
  int k = e >> 12, rem = e & 4095, cin = rem >> 6, cout = rem & 63;
  Wt[(k << 12) + (cout << 6) + cin] = f2bf(W[e]);
}

// ---- K1: compact keys + per-voxel point counts ------------------------------
__global__ void k1_keys(const int* __restrict__ coords, int* __restrict__ keys,
                        u32* __restrict__ lut) {
  int i = blockIdx.x * 256 + threadIdx.x;
  if (i >= NPTS) return;
  int4 c4 = *(const int4*)(coords + i * 4);
  int k = (c4.w << 21) | ((c4.x >> 1) << 14) | ((c4.y >> 1) << 7) | (c4.z >> 1);
  keys[i] = k;
  atomicAdd(&lut[k], 1u);   // count points per voxel (~600k atomics total)
}

// ---- K2a: per-chunk occupied-voxel counts -----------------------------------
__global__ void k2a_part(const u32* __restrict__ lut, u32* __restrict__ partials) {
  __shared__ u32 sd[256];
  int blk = blockIdx.x, t = threadIdx.x;
  const u32* p = lut + blk * CHUNK;
  u32 s = 0;
  for (int j = t; j < CHUNK; j += 256) s += (p[j] != 0u);
  sd[t] = s; __syncthreads();
  for (int o = 128; o > 0; o >>= 1) { if (t < o) sd[t] += sd[t + o]; __syncthreads(); }
  if (t == 0) partials[blk] = sd[0];
}

// ---- K2b: scan the 1024 partials (exclusive) + total U ----------------------
__global__ void k2b_top(u32* __restrict__ partials) {
  __shared__ u32 sh[NPART];
  int t = threadIdx.x;   // 1024 threads
  u32 x = partials[t];
  sh[t] = x; __syncthreads();
  for (int off = 1; off < NPART; off <<= 1) {
    u32 add = (t >= off) ? sh[t - off] : 0u;
    __syncthreads();
    sh[t] += add;
    __syncthreads();
  }
  partials[t] = sh[t] - x;                       // exclusive
  if (t == NPART - 1) partials[NPART] = sh[t];   // total unique count U
}

// ---- K2c: fill lut ((rank+1)|multi<<31 or 0), r2k, zero multi f32 rows ------
__global__ void k2c_fill(u32* __restrict__ lut, const u32* __restrict__ partials,
                         int* __restrict__ r2k, float* __restrict__ fds32) {
  __shared__ u32 tsum[256];
  int blk = blockIdx.x, t = threadIdx.x;
  int base = blk * CHUNK + t * 16;
  u32 loc[16]; u32 s = 0;
#pragma unroll
  for (int j = 0; j < 16; j++) { loc[j] = lut[base + j]; s += (loc[j] != 0u); }
  tsum[t] = s; __syncthreads();
  for (int off = 1; off < 256; off <<= 1) {
    u32 add = (t >= off) ? tsum[t - off] : 0u;
    __syncthreads();
    tsum[t] += add;
    __syncthreads();
  }
  u32 rank = partials[blk] + tsum[t] - s;   // exclusive rank for first elem
#pragma unroll
  for (int j = 0; j < 16; j++) {
    if (loc[j]) {
      u32 flag = (loc[j] > 1u) ? 0x80000000u : 0u;
      lut[base + j] = (rank + 1u) | flag;
      r2k[rank] = base + j;
      if (flag) {   // zero the f32 accumulation row for multi-point voxels
        float4 z = {0.f, 0.f, 0.f, 0.f};
        float* d = fds32 + ((size_t)rank << 6);
#pragma unroll
        for (int c = 0; c < 16; c++) *(float4*)(d + c * 4) = z;
      }
      rank++;
    } else lut[base + j] = 0u;
  }
}

// ---- K3: fused segment-sum: singles -> bf16 direct, multis -> f32 atomics ---
__global__ void k3_seg(const float* __restrict__ feats, const int* __restrict__ keys,
                       const u32* __restrict__ lut, float* __restrict__ fds32,
                       u16* __restrict__ fdsb) {
  int idx = blockIdx.x * 256 + threadIdx.x;   // NPTS*16 threads, 4 ch each
  if (idx >= NPTS * 16) return;
  int i = idx >> 4, q = (idx & 15) << 2;
  u32 lv = lut[keys[i]];
  u32 r = (lv & 0x7fffffffu) - 1u;
  float4 v = *(const float4*)(feats + (size_t)i * 64 + q);
  if (lv >> 31) {               // ~13% of points: shared voxel, accumulate f32
    float* dst = fds32 + ((size_t)r << 6) + q;
    atomicAdd(dst + 0, v.x); atomicAdd(dst + 1, v.y);
    atomicAdd(dst + 2, v.z); atomicAdd(dst + 3, v.w);
  } else {                      // ~87%: sole occupant, convert + plain store
    ushort4 o;
    o.x = f2bf(v.x); o.y = f2bf(v.y); o.z = f2bf(v.z); o.w = f2bf(v.w);
    *(ushort4*)(fdsb + ((size_t)r << 6) + q) = o;
  }
}

// ---- K3b: convert only multi-voxel rows f32 -> bf16 -------------------------
__global__ void k3b_fix(const int* __restrict__ r2k, const u32* __restrict__ lut,
                        const u32* __restrict__ pU,
                        const float* __restrict__ fds32, u16* __restrict__ fdsb) {
  int idx = blockIdx.x * 256 + threadIdx.x;   // NPTS*4 threads, 16 ch each
  int r = idx >> 2;
  if (r >= (int)(*pU)) return;
  u32 lv = lut[r2k[r]];
  if (!(lv >> 31)) return;
  int q = (idx & 3) << 4;
  const float* src = fds32 + ((size_t)r << 6) + q;
  u16* dst = fdsb + ((size_t)r << 6) + q;
#pragma unroll
  for (int j = 0; j < 4; j++) {
    float4 v = *(const float4*)(src + j * 4);
    ushort4 o;
    o.x = f2bf(v.x); o.y = f2bf(v.y); o.z = f2bf(v.z); o.w = f2bf(v.w);
    *(ushort4*)(dst + j * 4) = o;
  }
}

// ---- K4: 3-tile-per-barrier producer/consumer gather-GEMM + BN/ReLU ---------
// Block = 320 thr (5 waves), 64 output rows, 9 super-iterations of 3 tiles.
// Producer (w0) per super s, IN THIS ORDER:
//   1. DSW tiles 3s+3..3s+5  (regs loaded a FULL super ago -> any vmcnt wait,
//      even a conservative one, drains only long-completed loads)
//   2. LOADRG tiles 3s+6..3s+8 (exec-masked: ~13% of lanes issue requests)
//   3. PROBE tiles 3s+9..3s+11 (branchless, sentinel NKEYS)
// Consumers (w1-4): 3 tiles x (2 B-loads + 8 ds_reads + 8 MFMA) per barrier.
// Rings (re-derived): LDS slot t%6 — super s reads {3s..3s+2}%6, writes
// {3s+3..3s+5}%6 (disjoint; reuse across a barrier). rg[t%3] single set,
// written after its DSW consumer. lvr[t%6]: probed super s-1, used super s.
// 27 = 9x3 exactly. Raw s_barrier + lgkmcnt(0) (R9-verified), 10 barriers.
__global__ __launch_bounds__(320) void k4_conv(
    const u32* __restrict__ lut, const int* __restrict__ r2k,
    const u16* __restrict__ fdsb, const u16* __restrict__ Wt,
    const u32* __restrict__ pU, const float* __restrict__ ab,
    float* __restrict__ out) {
  __shared__ __align__(16) char ldsA[6][8192];   // ring-6: 64 rows x 128B
  const u32 U = *pU;
  int tid = threadIdx.x;
  int w = tid >> 6, l = tid & 63;
  // XCD-bijective swizzle (grid multiple of 8): rank-contiguous chunks per XCD.
  int bid = blockIdx.x;
  int cpx = (int)gridDim.x >> 3;
  int swz = (bid & 7) * cpx + (bid >> 3);
  int rbase = swz * 64;

  // ---- producer state (wave 0): lane l owns output row rbase + l ----
  int key = -1, x = 0, y = 0, z = 0;
  if (w == 0) {
    int r = rbase + l;
    key = ((u32)r < U) ? r2k[r] : -1;
    z = key & 127; y = (key >> 7) & 127; x = (key >> 14) & 127;
  }
  u32 lvr[6];          // probe ring: tile t probed one super before its LOADRG
  short8 rg[3][8];     // reg staging: tiles 3s+6..3s+8 -> rg[t%3]
  const short8 z8 = {0, 0, 0, 0, 0, 0, 0, 0};

#define PROBE(T) { \
    const int dx_ = (T) / 9 - 1, dy_ = ((T) / 3) % 3 - 1, dz_ = (T) % 3 - 1; \
    int nx_ = x + dx_, ny_ = y + dy_, nz_ = z + dz_; \
    bool ok_ = (key >= 0) & ((u32)nx_ < 128u) & ((u32)ny_ < 128u) & ((u32)nz_ < 128u); \
    int a_ = ok_ ? (key + dx_ * 16384 + dy_ * 128 + dz_) : NKEYS; \
    lvr[(T) % 6] = lut[a_]; }

  // exec-masked reg load of tile T (zeros on miss lanes; ~13% hit rate)
#define LOADRG(T) { \
    u32 lv_ = lvr[(T) % 6]; \
    _Pragma("unroll") for (int j = 0; j < 8; j++) rg[(T) % 3][j] = z8; \
    if (lv_) { \
      const u16* fr_ = fdsb + ((size_t)((lv_ & 0x7fffffffu) - 1u) << 6); \
      _Pragma("unroll") for (int j = 0; j < 8; j++) \
        rg[(T) % 3][j] = *(const short8*)(fr_ + j * 8); } }

  // LDS write of tile T (bank-rotated by row&7)
#define DSW(T) { \
    char* dst_ = &ldsA[(T) % 6][l * 128]; \
    int r7_ = l & 7; \
    _Pragma("unroll") for (int j = 0; j < 8; j++) \
      *(short8*)(dst_ + (((j + r7_) & 7) << 4)) = rg[(T) % 3][j]; }

  // ---- consumer state (waves 1-4): one 16-cout block each ----
  int ct = w - 1;
  int col = l & 15, kg = l >> 4;
  f32x4 acc[4] = {};   // 4 row-tiles of 16

#define CONSUME(K) { \
    const u16* wk_ = Wt + ((K) << 12) + (((ct << 4) + col) << 6) + (kg << 3); \
    short8 b0_ = *(const short8*)(wk_); \
    short8 b1_ = *(const short8*)(wk_ + 32); \
    const char* slab_ = &ldsA[(K) % 6][0]; \
    _Pragma("unroll") for (int rt = 0; rt < 4; rt++) { \
      int row_ = (rt << 4) + col; \
      const char* rp_ = slab_ + row_ * 128; \
      int r7_ = row_ & 7; \
      short8 a0_ = *(const short8*)(rp_ + (((kg + r7_) & 7) << 4)); \
      short8 a1_ = *(const short8*)(rp_ + (((kg + 4 + r7_) & 7) << 4)); \
      acc[rt] = __builtin_amdgcn_mfma_f32_16x16x32_bf16(a0_, b0_, acc[rt], 0, 0, 0); \
      acc[rt] = __builtin_amdgcn_mfma_f32_16x16x32_bf16(a1_, b1_, acc[rt], 0, 0, 0); } }

#define BAR() { \
    asm volatile("" ::: "memory"); \
    asm volatile("s_waitcnt lgkmcnt(0)" ::: "memory"); \
    __builtin_amdgcn_s_barrier(); \
    asm volatile("" ::: "memory"); }

  // prologue: tiles 0-2 in LDS; rg holds tiles 3-5; probes through tile 11
  if (w == 0) {
    PROBE(0) PROBE(1) PROBE(2) PROBE(3) PROBE(4) PROBE(5)
    LOADRG(0) LOADRG(1) LOADRG(2)
    DSW(0) DSW(1) DSW(2)
    PROBE(6) PROBE(7) PROBE(8)
    LOADRG(3) LOADRG(4) LOADRG(5)
    PROBE(9) PROBE(10) PROBE(11)
  }
  BAR()

  // super-iteration S: consume 3S..3S+2; stage per the header comment
#define SUPER(S) { \
    if (w == 0) { \
      if (3*(S)+3  < 27) DSW(3*(S)+3)  if (3*(S)+4  < 27) DSW(3*(S)+4)  if (3*(S)+5  < 27) DSW(3*(S)+5) \
      if (3*(S)+6  < 27) LOADRG(3*(S)+6)  if (3*(S)+7  < 27) LOADRG(3*(S)+7)  if (3*(S)+8  < 27) LOADRG(3*(S)+8) \
      if (3*(S)+9  < 27) PROBE(3*(S)+9)   if (3*(S)+10 < 27) PROBE(3*(S)+10)  if (3*(S)+11 < 27) PROBE(3*(S)+11) \
    } else { \
      CONSUME(3*(S)) CONSUME(3*(S)+1) CONSUME(3*(S)+2) \
    } \
    BAR() }

  SUPER(0) SUPER(1) SUPER(2) SUPER(3) SUPER(4)
  SUPER(5) SUPER(6) SUPER(7) SUPER(8)

#undef PROBE
#undef LOADRG
#undef DSW
#undef CONSUME
#undef BAR
#undef SUPER

  // epilogue (consumers): BN + ReLU, zeros for invalid (r >= U) rows
  if (w > 0) {
    int c = (ct << 4) | col;
    float al = ab[c], be = ab[64 + c];
#pragma unroll
    for (int rt = 0; rt < 4; rt++) {
#pragma unroll
      for (int i = 0; i < 4; i++) {
        int r = rbase + (rt << 4) + (kg << 2) + i;
        if (r >= NPTS) continue;
        bool valid = ((u32)r < U);
        float vv = 0.f;
        if (valid) {
          vv = fmaf(acc[rt][i], al, be);
          vv = vv > 0.f ? vv : 0.f;
        }
        out[((size_t)r << 6) + c] = vv;
      }
    }
  }
}

extern "C" void kernel_launch(void* const* d_in, const int* in_sizes, int n_in,
                              void* d_out, int out_size, void* d_ws, size_t ws_size,
                              hipStream_t stream) {
  const int*   coords = (const int*)d_in[0];
  const float* feats  = (const float*)d_in[1];
  const float* W      = (const float*)d_in[2];
  const float* bns    = (const float*)d_in[3];
  const float* bnb    = (const float*)d_in[4];
  const float* bnm    = (const float*)d_in[5];
  const float* bnv    = (const float*)d_in[6];
  float* out = (float*)d_out;

  char* ws = (char*)d_ws;
  size_t off = 0;
  auto alloc = [&](size_t bytes) -> void* {
    void* p = ws + off;
    off += (bytes + 255) & ~(size_t)255;
    return p;
  };
  u32* lut      = (u32*)alloc((size_t)(NKEYS + 1) * 4);  // +1 zero sentinel
  u32* partials = (u32*)alloc((NPART + 8) * 4);
  int* keys     = (int*)alloc((size_t)NPTS * 4);
  int* r2k      = (int*)alloc((size_t)NPTS * 4);
  u16* fdsb     = (u16*)alloc((size_t)(NPTS + 1) * 64 * 2);
  u16* Wt       = (u16*)alloc((size_t)27 * 4096 * 2);
  float* ab     = (float*)alloc(128 * 4);
  (void)ws_size; (void)out_size; (void)n_in; (void)in_sizes;

  float* fds32 = out;   // d_out doubles as f32 staging for multi-point voxels

  hipMemsetAsync(lut, 0, (size_t)(NKEYS + 1) * 4, stream);

  k0a_bn<<<1, 64, 0, stream>>>(bns, bnb, bnm, bnv, ab);
  k0b_wt<<<(27 * 4096 + 255) / 256, 256, 0, stream>>>(W, Wt);
  k1_keys<<<(NPTS + 255) / 256, 256, 0, stream>>>(coords, keys, lut);
  k2a_part<<<NPART, 256, 0, stream>>>(lut, partials);
  k2b_top<<<1, NPART, 0, stream>>>(partials);
  k2c_fill<<<NPART, 256, 0, stream>>>(lut, partials, r2k, fds32);
  k3_seg<<<(NPTS * 16 + 255) / 256, 256, 0, stream>>>(feats, keys, lut, fds32, fdsb);
  k3b_fix<<<(NPTS * 4 + 255) / 256, 256, 0, stream>>>(r2k, lut, partials + NPART, fds32, fdsb);
  // 64 rows per block; 9376 blocks (multiple of 8 for the XCD swizzle)
  k4_conv<<<(NPTS + 63) / 64, 320, 0, stream>>>(lut, r2k, fdsb, Wt,
                                                partials + NPART, ab, out);
}